// Round 10
// baseline (122.273 us; speedup 1.0000x reference)
//
#include <hip/hip_runtime.h>

// LimitedKVWithBBPM — round 10.
// r9 landed bf16-acc + 4 dispatches (117.5us). This round: metadata-chain
// trims. (1) qflag packed into cnt word (bit 30 via atomicOr; count in low
// 24 bits) -> reduce does ONE metadata load per slot, not two. (2) pos_table
// as u16 (j+1 encoding) -> 512KB, L2-resident for gather's random probes.
// (3) memset down to ~1MB. Structure otherwise r9 (its measured floor).

typedef float f32x4 __attribute__((ext_vector_type(4)));
typedef int   i32x4 __attribute__((ext_vector_type(4)));
typedef unsigned short u16x4 __attribute__((ext_vector_type(4)));

constexpr int DIM    = 128;
constexpr int MEM    = 131072;       // 2^17 -> mask
constexpr int KCACHE = 8192;
constexpr int CAP    = 8;            // token bucket capacity (mean load 2)
constexpr unsigned FLAG = 1u << 30;  // query flag bit in cntflag word
constexpr unsigned CMSK = 0x00FFFFFF;// count field (n << 2^24 assumed)

__device__ __forceinline__ f32x4 ldrow(const float* __restrict__ p, int q) {
    return *reinterpret_cast<const f32x4*>(p + q * 4);
}
__device__ __forceinline__ f32x4 nt_ldrow(const float* __restrict__ p, int q) {
    return __builtin_nontemporal_load(reinterpret_cast<const f32x4*>(p) + q);
}
__device__ __forceinline__ void nt_strow(float* __restrict__ p, int q, f32x4 v) {
    __builtin_nontemporal_store(v, reinterpret_cast<f32x4*>(p) + q);
}
__device__ __forceinline__ unsigned short f2bf(float x) {   // RNE round
    union { float f; unsigned u; } c; c.f = x;
    unsigned r = c.u + 0x7FFF + ((c.u >> 16) & 1);
    return (unsigned short)(r >> 16);
}
__device__ __forceinline__ u16x4 pack_bf(f32x4 v) {
    u16x4 h; h.x = f2bf(v.x); h.y = f2bf(v.y); h.z = f2bf(v.z); h.w = f2bf(v.w);
    return h;
}
__device__ __forceinline__ f32x4 unpack_bf(u16x4 h) {
    union { unsigned u; float f; } a, b, c, d;
    a.u = (unsigned)h.x << 16; b.u = (unsigned)h.y << 16;
    c.u = (unsigned)h.z << 16; d.u = (unsigned)h.w << 16;
    f32x4 v; v.x = a.f; v.y = b.f; v.z = c.f; v.w = d.f;
    return v;
}

// Fused front end: bucket fill (atomicAdd on count field) + query-slot flag
// (atomicOr bit 30, same word) + pos_table u16 build + sequential vals stream.
__global__ void front_kernel(const int* __restrict__ keys,
                             unsigned* __restrict__ cntflag,
                             int* __restrict__ bucket,
                             int* __restrict__ ovf_cnt, int* __restrict__ ovf,
                             const int* __restrict__ qkeys,
                             const int* __restrict__ positions,
                             unsigned short* __restrict__ pos_table,
                             const f32x4* __restrict__ vals4,
                             int n, int nv4) {
    int tid = blockIdx.x * 256 + threadIdx.x;

    if (tid < n) {
        int slot = ((unsigned)keys[tid]) & (MEM - 1);
        unsigned old = atomicAdd(&cntflag[slot], 1u);
        int pos = (int)(old & CMSK);
        if (pos < CAP) bucket[slot * CAP + pos] = tid;
        else { int k = atomicAdd(ovf_cnt, 1); ovf[k] = tid; }
        atomicOr(&cntflag[((unsigned)qkeys[tid]) & (MEM - 1)], FLAG);
    }
    if (tid < KCACHE) {
        int p = positions[n - KCACHE + tid];
        if (p >= 0 && p < n) pos_table[p] = (unsigned short)(tid + 1); // 0=empty
    }
    // sequential per-block chunk of vals -> L3
    int chunk = (nv4 + gridDim.x - 1) / gridDim.x;
    int beg = blockIdx.x * chunk;
    int end = beg + chunk; if (end > nv4) end = nv4;
    float s = 0.f;
    for (int t = beg + (int)threadIdx.x; t < end; t += 256) {
        f32x4 v = vals4[t];
        s += v.x + v.y + v.z + v.w;
    }
    asm volatile("" :: "v"(s));   // keep stream live (rule #17)
}

// Dedup slot sums -> bf16 acc. 2 slots per 32-lane group, 16 per block.
// ONE metadata word per slot (flag|count) + bucket quad; fp32 accumulation
// in-register, one bf16 round on store. Overflow (count>CAP) scans ovf list.
__global__ void __launch_bounds__(256, 8)
reduce_kernel(const float* __restrict__ vals,
              const float* __restrict__ bbpm,
              const int* __restrict__ keys,
              const unsigned* __restrict__ cntflag,
              const int* __restrict__ bucket,
              const int* __restrict__ ovf_cnt,
              const int* __restrict__ ovf,
              unsigned short* __restrict__ acc16) {
    int g = threadIdx.x >> 5;
    int q = threadIdx.x & 31;
    int s0 = blockIdx.x * 16 + g;
    int s1 = s0 + 8;

    unsigned w0 = cntflag[s0], w1 = cntflag[s1];
    i32x4 b0 = *reinterpret_cast<const i32x4*>(bucket + s0 * CAP);
    i32x4 b1 = *reinterpret_cast<const i32x4*>(bucket + s1 * CAP);
    int f0 = (w0 & FLAG) ? 1 : 0, f1 = (w1 & FLAG) ? 1 : 0;
    if ((f0 | f1) == 0) return;

    int n0 = (int)(w0 & CMSK), n1 = (int)(w1 & CMSK);
    int c0 = f0 ? (n0 > CAP ? CAP : n0) : 0;
    int c1 = f1 ? (n1 > CAP ? CAP : n1) : 0;

    int r00 = c0 > 0 ? b0.x : 0, r01 = c0 > 1 ? b0.y : 0;
    int r10 = c1 > 0 ? b1.x : 0, r11 = c1 > 1 ? b1.y : 0;
    float m00 = c0 > 0 ? 1.f : 0.f, m01 = c0 > 1 ? 1.f : 0.f;
    float m10 = c1 > 0 ? 1.f : 0.f, m11 = c1 > 1 ? 1.f : 0.f;

    const float* bb0 = bbpm + (f0 ? (size_t)s0 * DIM : 0);
    const float* bb1 = bbpm + (f1 ? (size_t)s1 * DIM : 0);
    f32x4 A0  = nt_ldrow(bb0, q);
    f32x4 A1  = nt_ldrow(bb1, q);
    f32x4 V00 = ldrow(vals + (size_t)r00 * DIM, q);
    f32x4 V01 = ldrow(vals + (size_t)r01 * DIM, q);
    f32x4 V10 = ldrow(vals + (size_t)r10 * DIM, q);
    f32x4 V11 = ldrow(vals + (size_t)r11 * DIM, q);

    f32x4 a0 = A0 + m00 * V00 + m01 * V01;
    f32x4 a1 = A1 + m10 * V10 + m11 * V11;

    if (c0 > 2) {
        a0 += ldrow(vals + (size_t)b0.z * DIM, q);
        if (c0 > 3) {
            a0 += ldrow(vals + (size_t)b0.w * DIM, q);
            for (int j = 4; j < c0; ++j)
                a0 += ldrow(vals + (size_t)bucket[s0 * CAP + j] * DIM, q);
        }
        if (n0 > CAP) {                           // pathological keys only
            int L = *ovf_cnt;
            for (int j = 0; j < L; ++j) {
                int i = ovf[j];
                if ((((unsigned)keys[i]) & (MEM - 1)) == (unsigned)s0)
                    a0 += ldrow(vals + (size_t)i * DIM, q);
            }
        }
    }
    if (c1 > 2) {
        a1 += ldrow(vals + (size_t)b1.z * DIM, q);
        if (c1 > 3) {
            a1 += ldrow(vals + (size_t)b1.w * DIM, q);
            for (int j = 4; j < c1; ++j)
                a1 += ldrow(vals + (size_t)bucket[s1 * CAP + j] * DIM, q);
        }
        if (n1 > CAP) {
            int L = *ovf_cnt;
            for (int j = 0; j < L; ++j) {
                int i = ovf[j];
                if ((((unsigned)keys[i]) & (MEM - 1)) == (unsigned)s1)
                    a1 += ldrow(vals + (size_t)i * DIM, q);
            }
        }
    }

    if (f0) *reinterpret_cast<u16x4*>(acc16 + (size_t)s0 * DIM + q * 4) = pack_bf(a0);
    if (f1) *reinterpret_cast<u16x4*>(acc16 + (size_t)s1 * DIM + q * 4) = pack_bf(a1);
}

// 4 output rows per 32-lane group. u16 pos_table probe (L2-resident);
// hit -> fp32 vals row; miss -> bf16 acc row. Sequential NT out writes.
__global__ void gather_kernel(const float* __restrict__ vals,
                              const unsigned short* __restrict__ acc16,
                              const int* __restrict__ qkeys,
                              const int* __restrict__ qpos,
                              const unsigned short* __restrict__ pos_table,
                              float* __restrict__ out, int n, int base) {
    int g = threadIdx.x >> 5;
    int q = threadIdx.x & 31;
    int r0 = blockIdx.x * 32 + g;
    int r1 = r0 + 8, r2 = r0 + 16, r3 = r0 + 24;

    bool k0 = r0 < n, k1 = r1 < n, k2 = r2 < n, k3 = r3 < n;
    int qp0 = k0 ? qpos[r0] : -1, qp1 = k1 ? qpos[r1] : -1;
    int qp2 = k2 ? qpos[r2] : -1, qp3 = k3 ? qpos[r3] : -1;
    int qk0 = k0 ? qkeys[r0] : 0, qk1 = k1 ? qkeys[r1] : 0;
    int qk2 = k2 ? qkeys[r2] : 0, qk3 = k3 ? qkeys[r3] : 0;

    int i0 = (qp0 >= 0 && qp0 < n) ? (int)pos_table[qp0] - 1 : -1;
    int i1 = (qp1 >= 0 && qp1 < n) ? (int)pos_table[qp1] - 1 : -1;
    int i2 = (qp2 >= 0 && qp2 < n) ? (int)pos_table[qp2] - 1 : -1;
    int i3 = (qp3 >= 0 && qp3 < n) ? (int)pos_table[qp3] - 1 : -1;

    f32x4 v0, v1, v2, v3;
    if (i0 >= 0) v0 = ldrow(vals + (size_t)(base + i0) * DIM, q);
    else v0 = unpack_bf(*reinterpret_cast<const u16x4*>(
                 acc16 + (size_t)(((unsigned)qk0) & (MEM - 1)) * DIM + q * 4));
    if (i1 >= 0) v1 = ldrow(vals + (size_t)(base + i1) * DIM, q);
    else v1 = unpack_bf(*reinterpret_cast<const u16x4*>(
                 acc16 + (size_t)(((unsigned)qk1) & (MEM - 1)) * DIM + q * 4));
    if (i2 >= 0) v2 = ldrow(vals + (size_t)(base + i2) * DIM, q);
    else v2 = unpack_bf(*reinterpret_cast<const u16x4*>(
                 acc16 + (size_t)(((unsigned)qk2) & (MEM - 1)) * DIM + q * 4));
    if (i3 >= 0) v3 = ldrow(vals + (size_t)(base + i3) * DIM, q);
    else v3 = unpack_bf(*reinterpret_cast<const u16x4*>(
                 acc16 + (size_t)(((unsigned)qk3) & (MEM - 1)) * DIM + q * 4));

    if (k0) nt_strow(out + (size_t)r0 * DIM, q, v0);
    if (k1) nt_strow(out + (size_t)r1 * DIM, q, v1);
    if (k2) nt_strow(out + (size_t)r2 * DIM, q, v2);
    if (k3) nt_strow(out + (size_t)r3 * DIM, q, v3);
}

extern "C" void kernel_launch(void* const* d_in, const int* in_sizes, int n_in,
                              void* d_out, int out_size, void* d_ws, size_t ws_size,
                              hipStream_t stream) {
    const int*   keys      = (const int*)d_in[0];
    const float* vals      = (const float*)d_in[1];
    const int*   positions = (const int*)d_in[2];
    const int*   qkeys     = (const int*)d_in[3];
    const int*   qpos      = (const int*)d_in[4];
    const float* bbpm      = (const float*)d_in[5];
    float* out = (float*)d_out;

    const int n = in_sizes[0];                  // B*T tokens

    // ws layout: [cntflag MEM u32][ctrs 64 u32][pos_table n u16]  <- one memset
    //            [bucket MEM*CAP][ovf n][acc16 MEM*DIM u16]
    char* ws = (char*)d_ws;
    unsigned*       cntflag   = (unsigned*)ws;
    int*            ctrs      = (int*)(cntflag + MEM);        // [0] = ovf_cnt
    unsigned short* pos_table = (unsigned short*)(ctrs + 64);
    int*            bucket    = (int*)(pos_table + ((n + 1) & ~1));
    int*            ovf       = bucket + MEM * CAP;
    unsigned short* acc16     = (unsigned short*)(ovf + n);

    size_t zero_bytes = (size_t)MEM * 4 + 256 + (size_t)n * 2;
    hipMemsetAsync(cntflag, 0, zero_bytes, stream);

    front_kernel<<<(n + 255) / 256, 256, 0, stream>>>(
        keys, cntflag, bucket, &ctrs[0], ovf, qkeys,
        positions, pos_table, (const f32x4*)vals, n, n * (DIM / 4));
    reduce_kernel<<<MEM / 16, 256, 0, stream>>>(
        vals, bbpm, keys, cntflag, bucket, &ctrs[0], ovf, acc16);
    gather_kernel<<<(n + 31) / 32, 256, 0, stream>>>(
        vals, acc16, qkeys, qpos, pos_table, out, n, n - KCACHE);
}

// Round 11
// 116.196 us; speedup vs baseline: 1.0523x; 1.0523x over previous
//
#include <hip/hip_runtime.h>

// LimitedKVWithBBPM — round 11.
// r10 lesson: atomicOr(qflag into cntflag) contends with the fill atomicAdd
// on the same lines (+5us); plain-store qflag (r9) is the right mechanism.
// This round = r9 structure exactly, keeping only r10's harmless wins:
// u16 pos_table (L2-resident) and single ~1.5MB memset.

typedef float f32x4 __attribute__((ext_vector_type(4)));
typedef int   i32x4 __attribute__((ext_vector_type(4)));
typedef unsigned short u16x4 __attribute__((ext_vector_type(4)));

constexpr int DIM    = 128;
constexpr int MEM    = 131072;   // 2^17 -> mask
constexpr int KCACHE = 8192;
constexpr int CAP    = 8;        // token bucket capacity (mean load 2)

__device__ __forceinline__ f32x4 ldrow(const float* __restrict__ p, int q) {
    return *reinterpret_cast<const f32x4*>(p + q * 4);
}
__device__ __forceinline__ f32x4 nt_ldrow(const float* __restrict__ p, int q) {
    return __builtin_nontemporal_load(reinterpret_cast<const f32x4*>(p) + q);
}
__device__ __forceinline__ void nt_strow(float* __restrict__ p, int q, f32x4 v) {
    __builtin_nontemporal_store(v, reinterpret_cast<f32x4*>(p) + q);
}
__device__ __forceinline__ unsigned short f2bf(float x) {   // RNE round
    union { float f; unsigned u; } c; c.f = x;
    unsigned r = c.u + 0x7FFF + ((c.u >> 16) & 1);
    return (unsigned short)(r >> 16);
}
__device__ __forceinline__ u16x4 pack_bf(f32x4 v) {
    u16x4 h; h.x = f2bf(v.x); h.y = f2bf(v.y); h.z = f2bf(v.z); h.w = f2bf(v.w);
    return h;
}
__device__ __forceinline__ f32x4 unpack_bf(u16x4 h) {
    union { unsigned u; float f; } a, b, c, d;
    a.u = (unsigned)h.x << 16; b.u = (unsigned)h.y << 16;
    c.u = (unsigned)h.z << 16; d.u = (unsigned)h.w << 16;
    f32x4 v; v.x = a.f; v.y = b.f; v.z = c.f; v.w = d.f;
    return v;
}

// Fused front end: bucket fill + qflag (plain store, ALL query slots) +
// u16 pos_table build + sequential vals stream (warms L3 for reduce).
__global__ void front_kernel(const int* __restrict__ keys,
                             int* __restrict__ cnt, int* __restrict__ bucket,
                             int* __restrict__ ovf_cnt, int* __restrict__ ovf,
                             const int* __restrict__ qkeys,
                             int* __restrict__ qflag,
                             const int* __restrict__ positions,
                             unsigned short* __restrict__ pos_table,
                             const f32x4* __restrict__ vals4,
                             int n, int nv4) {
    int tid = blockIdx.x * 256 + threadIdx.x;

    if (tid < n) {
        int slot = ((unsigned)keys[tid]) & (MEM - 1);
        int pos = atomicAdd(&cnt[slot], 1);
        if (pos < CAP) bucket[slot * CAP + pos] = tid;
        else { int k = atomicAdd(ovf_cnt, 1); ovf[k] = tid; }
        // plain store (r9-proven): no atomic round-trip
        qflag[((unsigned)qkeys[tid]) & (MEM - 1)] = 1;
    }
    if (tid < KCACHE) {
        int p = positions[n - KCACHE + tid];
        if (p >= 0 && p < n) pos_table[p] = (unsigned short)(tid + 1); // 0=empty
    }
    // sequential per-block chunk of vals -> L3
    int chunk = (nv4 + gridDim.x - 1) / gridDim.x;
    int beg = blockIdx.x * chunk;
    int end = beg + chunk; if (end > nv4) end = nv4;
    float s = 0.f;
    for (int t = beg + (int)threadIdx.x; t < end; t += 256) {
        f32x4 v = vals4[t];
        s += v.x + v.y + v.z + v.w;
    }
    asm volatile("" :: "v"(s));   // keep stream live (rule #17)
}

// Dedup slot sums -> bf16 acc. 2 slots per 32-lane group, 16 per block.
// qflag/cnt/bucket loaded in parallel; fp32 accumulation in-register, one
// bf16 round on store. Overflow (cnt>CAP) scans the tiny ovf list inline.
__global__ void __launch_bounds__(256, 8)
reduce_kernel(const float* __restrict__ vals,
              const float* __restrict__ bbpm,
              const int* __restrict__ keys,
              const int* __restrict__ cnt,
              const int* __restrict__ qflag,
              const int* __restrict__ bucket,
              const int* __restrict__ ovf_cnt,
              const int* __restrict__ ovf,
              unsigned short* __restrict__ acc16) {
    int g = threadIdx.x >> 5;
    int q = threadIdx.x & 31;
    int s0 = blockIdx.x * 16 + g;
    int s1 = s0 + 8;

    int f0 = qflag[s0], f1 = qflag[s1];
    int n0 = cnt[s0],   n1 = cnt[s1];
    i32x4 b0 = *reinterpret_cast<const i32x4*>(bucket + s0 * CAP);
    i32x4 b1 = *reinterpret_cast<const i32x4*>(bucket + s1 * CAP);
    if ((f0 | f1) == 0) return;

    int c0 = f0 ? (n0 > CAP ? CAP : n0) : 0;
    int c1 = f1 ? (n1 > CAP ? CAP : n1) : 0;

    int r00 = c0 > 0 ? b0.x : 0, r01 = c0 > 1 ? b0.y : 0;
    int r10 = c1 > 0 ? b1.x : 0, r11 = c1 > 1 ? b1.y : 0;
    float m00 = c0 > 0 ? 1.f : 0.f, m01 = c0 > 1 ? 1.f : 0.f;
    float m10 = c1 > 0 ? 1.f : 0.f, m11 = c1 > 1 ? 1.f : 0.f;

    const float* bb0 = bbpm + (f0 ? (size_t)s0 * DIM : 0);
    const float* bb1 = bbpm + (f1 ? (size_t)s1 * DIM : 0);
    f32x4 A0  = nt_ldrow(bb0, q);
    f32x4 A1  = nt_ldrow(bb1, q);
    f32x4 V00 = ldrow(vals + (size_t)r00 * DIM, q);
    f32x4 V01 = ldrow(vals + (size_t)r01 * DIM, q);
    f32x4 V10 = ldrow(vals + (size_t)r10 * DIM, q);
    f32x4 V11 = ldrow(vals + (size_t)r11 * DIM, q);

    f32x4 a0 = A0 + m00 * V00 + m01 * V01;
    f32x4 a1 = A1 + m10 * V10 + m11 * V11;

    if (c0 > 2) {
        a0 += ldrow(vals + (size_t)b0.z * DIM, q);
        if (c0 > 3) {
            a0 += ldrow(vals + (size_t)b0.w * DIM, q);
            for (int j = 4; j < c0; ++j)
                a0 += ldrow(vals + (size_t)bucket[s0 * CAP + j] * DIM, q);
        }
        if (n0 > CAP) {                           // pathological keys only
            int L = *ovf_cnt;
            for (int j = 0; j < L; ++j) {
                int i = ovf[j];
                if ((((unsigned)keys[i]) & (MEM - 1)) == (unsigned)s0)
                    a0 += ldrow(vals + (size_t)i * DIM, q);
            }
        }
    }
    if (c1 > 2) {
        a1 += ldrow(vals + (size_t)b1.z * DIM, q);
        if (c1 > 3) {
            a1 += ldrow(vals + (size_t)b1.w * DIM, q);
            for (int j = 4; j < c1; ++j)
                a1 += ldrow(vals + (size_t)bucket[s1 * CAP + j] * DIM, q);
        }
        if (n1 > CAP) {
            int L = *ovf_cnt;
            for (int j = 0; j < L; ++j) {
                int i = ovf[j];
                if ((((unsigned)keys[i]) & (MEM - 1)) == (unsigned)s1)
                    a1 += ldrow(vals + (size_t)i * DIM, q);
            }
        }
    }

    if (f0) *reinterpret_cast<u16x4*>(acc16 + (size_t)s0 * DIM + q * 4) = pack_bf(a0);
    if (f1) *reinterpret_cast<u16x4*>(acc16 + (size_t)s1 * DIM + q * 4) = pack_bf(a1);
}

// 4 output rows per 32-lane group. u16 pos_table probe (512KB, L2-resident);
// hit -> fp32 vals row; miss -> bf16 acc row. Sequential NT out writes.
__global__ void gather_kernel(const float* __restrict__ vals,
                              const unsigned short* __restrict__ acc16,
                              const int* __restrict__ qkeys,
                              const int* __restrict__ qpos,
                              const unsigned short* __restrict__ pos_table,
                              float* __restrict__ out, int n, int base) {
    int g = threadIdx.x >> 5;
    int q = threadIdx.x & 31;
    int r0 = blockIdx.x * 32 + g;
    int r1 = r0 + 8, r2 = r0 + 16, r3 = r0 + 24;

    bool k0 = r0 < n, k1 = r1 < n, k2 = r2 < n, k3 = r3 < n;
    int qp0 = k0 ? qpos[r0] : -1, qp1 = k1 ? qpos[r1] : -1;
    int qp2 = k2 ? qpos[r2] : -1, qp3 = k3 ? qpos[r3] : -1;
    int qk0 = k0 ? qkeys[r0] : 0, qk1 = k1 ? qkeys[r1] : 0;
    int qk2 = k2 ? qkeys[r2] : 0, qk3 = k3 ? qkeys[r3] : 0;

    int i0 = (qp0 >= 0 && qp0 < n) ? (int)pos_table[qp0] - 1 : -1;
    int i1 = (qp1 >= 0 && qp1 < n) ? (int)pos_table[qp1] - 1 : -1;
    int i2 = (qp2 >= 0 && qp2 < n) ? (int)pos_table[qp2] - 1 : -1;
    int i3 = (qp3 >= 0 && qp3 < n) ? (int)pos_table[qp3] - 1 : -1;

    f32x4 v0, v1, v2, v3;
    if (i0 >= 0) v0 = ldrow(vals + (size_t)(base + i0) * DIM, q);
    else v0 = unpack_bf(*reinterpret_cast<const u16x4*>(
                 acc16 + (size_t)(((unsigned)qk0) & (MEM - 1)) * DIM + q * 4));
    if (i1 >= 0) v1 = ldrow(vals + (size_t)(base + i1) * DIM, q);
    else v1 = unpack_bf(*reinterpret_cast<const u16x4*>(
                 acc16 + (size_t)(((unsigned)qk1) & (MEM - 1)) * DIM + q * 4));
    if (i2 >= 0) v2 = ldrow(vals + (size_t)(base + i2) * DIM, q);
    else v2 = unpack_bf(*reinterpret_cast<const u16x4*>(
                 acc16 + (size_t)(((unsigned)qk2) & (MEM - 1)) * DIM + q * 4));
    if (i3 >= 0) v3 = ldrow(vals + (size_t)(base + i3) * DIM, q);
    else v3 = unpack_bf(*reinterpret_cast<const u16x4*>(
                 acc16 + (size_t)(((unsigned)qk3) & (MEM - 1)) * DIM + q * 4));

    if (k0) nt_strow(out + (size_t)r0 * DIM, q, v0);
    if (k1) nt_strow(out + (size_t)r1 * DIM, q, v1);
    if (k2) nt_strow(out + (size_t)r2 * DIM, q, v2);
    if (k3) nt_strow(out + (size_t)r3 * DIM, q, v3);
}

extern "C" void kernel_launch(void* const* d_in, const int* in_sizes, int n_in,
                              void* d_out, int out_size, void* d_ws, size_t ws_size,
                              hipStream_t stream) {
    const int*   keys      = (const int*)d_in[0];
    const float* vals      = (const float*)d_in[1];
    const int*   positions = (const int*)d_in[2];
    const int*   qkeys     = (const int*)d_in[3];
    const int*   qpos      = (const int*)d_in[4];
    const float* bbpm      = (const float*)d_in[5];
    float* out = (float*)d_out;

    const int n = in_sizes[0];                  // B*T tokens

    // ws layout: [cnt MEM][qflag MEM][ctrs 64][pos_table n u16] <- one memset
    //            [bucket MEM*CAP][ovf n][acc16 MEM*DIM u16]
    char* ws = (char*)d_ws;
    int*            cnt       = (int*)ws;
    int*            qflag     = cnt + MEM;
    int*            ctrs      = qflag + MEM;          // [0] = ovf_cnt
    unsigned short* pos_table = (unsigned short*)(ctrs + 64);
    int*            bucket    = (int*)(pos_table + ((n + 1) & ~1));
    int*            ovf       = bucket + MEM * CAP;
    unsigned short* acc16     = (unsigned short*)(ovf + n);

    size_t zero_bytes = (size_t)(2 * MEM + 64) * 4 + (size_t)n * 2;
    hipMemsetAsync(cnt, 0, zero_bytes, stream);

    front_kernel<<<(n + 255) / 256, 256, 0, stream>>>(
        keys, cnt, bucket, &ctrs[0], ovf, qkeys, qflag,
        positions, pos_table, (const f32x4*)vals, n, n * (DIM / 4));
    reduce_kernel<<<MEM / 16, 256, 0, stream>>>(
        vals, bbpm, keys, cnt, qflag, bucket, &ctrs[0], ovf, acc16);
    gather_kernel<<<(n + 31) / 32, 256, 0, stream>>>(
        vals, acc16, qkeys, qpos, pos_table, out, n, n - KCACHE);
}